// Round 1
// 504.666 us; speedup vs baseline: 1.4804x; 1.4804x over previous
//
#include <hip/hip_runtime.h>
#include <math.h>

#define NEARZERO 1e-5f
#define LENF 15

// ---- LDS ring geometry -----------------------------------------------------
// Each step-slot: 4KB param slab (praw[t, n0:n0+16, 0:16, 0:4], contiguous)
// staged as 4 x 1KB global_load_lds(width=16) chunks with 16B inter-chunk pad,
// plus a 192B forcing slab (x[t, n0:n0+16, 0:3]) staged with one width=4 load.
#define KB 7                                   // steps per batch
#define CHUNK_STRIDE (1024 + 16)               // 1040 B
#define SLOT_PARAM (4 * CHUNK_STRIDE)          // 4160 B
#define SLOT_BYTES (SLOT_PARAM + 192)          // 4352 B (16B-aligned)
#define BUF_BYTES (KB * SLOT_BYTES)            // 30464 B
#define LDS_BYTES (2 * BUF_BYTES)              // 60928 B (< 64KB static limit)

// s_waitcnt immediates (gfx9: vmcnt[3:0]|[15:14], exp[6:4], lgkm[11:8])
#define WAIT_VMCNT_35 0x8F73                   // vmcnt(35), lgkm/exp don't-care
#define WAIT_LGKM_0   0xC07F                   // lgkmcnt(0), vmcnt/exp don't-care

#define GPTR(p) ((const __attribute__((address_space(1))) void*)(p))
#define LPTR(p) ((__attribute__((address_space(3))) void*)(p))

// DPP quad_perm swaps within each quad of lanes (VALU, no LDS).
__device__ __forceinline__ float qswap1(float v) {
    return __int_as_float(__builtin_amdgcn_update_dpp(
        0, __float_as_int(v), 0xB1 /* quad_perm(1,0,3,2) */, 0xF, 0xF, true));
}
__device__ __forceinline__ float qswap2(float v) {
    return __int_as_float(__builtin_amdgcn_update_dpp(
        0, __float_as_int(v), 0x4E /* quad_perm(2,3,0,1) */, 0xF, 0xF, true));
}

// Fast x^y for x > 0 via the single-instruction hardware transcendentals
// v_log_f32 (log2) and v_exp_f32 (exp2). HIP's __powf is NOT the CUDA fast
// path -- it maps to __ocml_pow_f32 (accurate OCML pow, hundreds of VALU ops
// inlined). Both call sites feed a clip to [0,1] and have provably-positive
// arguments (SM >= NEARZERO, FC/LP > 0), so the 3-op form is safe.
__device__ __forceinline__ float powpos(float x, float y) {
    return __builtin_amdgcn_exp2f(y * __builtin_amdgcn_logf(x));
}

// Stage one batch (KB steps). 5 vmem instructions per step = 35 per batch,
// ALWAYS issued (t clamped) so the vmcnt arithmetic stays exact.
__device__ __forceinline__ void stage_batch(const float* __restrict__ praw,
                                            const float* __restrict__ x,
                                            char* smem, int buf, int t0,
                                            int T, int N, int n0, int lane)
{
    char* bufp = smem + buf * BUF_BYTES;
    for (int s = 0; s < KB; ++s) {
        int ts = t0 + s;
        if (ts > T - 1) ts = T - 1;
        const float* gp = praw + (size_t)ts * (size_t)(N * 64) + (size_t)n0 * 64;
        char* sp = bufp + s * SLOT_BYTES;
#pragma unroll
        for (int c = 0; c < 4; ++c) {
            __builtin_amdgcn_global_load_lds(GPTR(gp + c * 256 + lane * 4),
                                             LPTR(sp + c * CHUNK_STRIDE),
                                             16, 0, 0);
        }
        const float* xg = x + (size_t)ts * (size_t)(N * 3) + (size_t)n0 * 3;
        if (lane < 48) {
            __builtin_amdgcn_global_load_lds(GPTR(xg + lane),
                                             LPTR(sp + SLOT_PARAM),
                                             4, 0, 0);
        }
    }
}

__device__ __forceinline__ float dostep(const float* __restrict__ pr, // 14 regs
                                        float P, float Ta, float PET,
                                        float& SNOWPACK, float& MELTWATER,
                                        float& SM, float& SUZ, float& SLZ)
{
    // TT is the only jump-discontinuous parameter (Ta >= TT): compute with
    // unfused mul+add to bit-match numpy's lo + raw*(hi-lo).
    const float BETA   = fmaf(pr[0],  5.0f,   1.0f);
    const float FC     = fmaf(pr[1],  950.0f, 50.0f);
    const float K0     = fmaf(pr[2],  0.85f,  0.05f);
    const float K1     = fmaf(pr[3],  0.49f,  0.01f);
    const float K2     = fmaf(pr[4],  0.199f, 0.001f);
    const float LP     = fmaf(pr[5],  0.8f,   0.2f);
    const float PERC   = pr[6] * 10.0f;
    const float UZL    = pr[7] * 100.0f;
    const float TT     = __fadd_rn(-2.5f, __fmul_rn(pr[8], 5.0f));
    const float CFMAX  = fmaf(pr[9],  9.5f,   0.5f);
    const float CFR    = pr[10] * 0.1f;
    const float CWH    = pr[11] * 0.2f;
    const float BETAET = fmaf(pr[12], 4.7f,   0.3f);
    const float C      = pr[13];

    const bool  wet  = (Ta >= TT);
    const float RAIN = wet ? P : 0.0f;
    const float SNOW = wet ? 0.0f : P;

    SNOWPACK += SNOW;
    const float melt = fminf(fmaxf(CFMAX * (Ta - TT), 0.0f), SNOWPACK);
    MELTWATER += melt;
    SNOWPACK = fmaxf(SNOWPACK - melt, NEARZERO);
    const float refreeze = fminf(fmaxf(CFR * CFMAX * (TT - Ta), 0.0f), MELTWATER);
    SNOWPACK += refreeze;
    MELTWATER = fmaxf(MELTWATER - refreeze, NEARZERO);
    const float tosoil = fmaxf(MELTWATER - CWH * SNOWPACK, 0.0f);
    MELTWATER = fmaxf(MELTWATER - tosoil, NEARZERO);

    const float rFC = __frcp_rn(FC);
    float soil_wet = powpos(SM * rFC, BETA);
    soil_wet = fminf(fmaxf(soil_wet, 0.0f), 1.0f);
    const float recharge = (RAIN + tosoil) * soil_wet;
    SM = SM + RAIN + tosoil - recharge;
    const float excess = fmaxf(SM - FC, 0.0f);
    SM = fmaxf(SM - excess, NEARZERO);

    float evapfactor = powpos(SM * __frcp_rn(LP * FC), BETAET);
    evapfactor = fminf(fmaxf(evapfactor, 0.0f), 1.0f);
    const float ETact = fminf(SM, PET * evapfactor);
    SM = fmaxf(SM - ETact, NEARZERO);

    const float capillary = fminf(SLZ, C * SLZ * (1.0f - fminf(SM * rFC, 1.0f)));
    SM += capillary;
    SLZ = fmaxf(SLZ - capillary, NEARZERO);

    SUZ = SUZ + recharge + excess;
    const float PERCa = fminf(SUZ, PERC);
    SUZ -= PERCa;
    const float Q0 = K0 * fmaxf(SUZ - UZL, 0.0f);
    SUZ -= Q0;
    const float Q1 = K1 * SUZ;
    SUZ -= Q1;
    SLZ += PERCa;
    const float Q2 = K2 * SLZ;
    SLZ -= Q2;
    return Q0 + Q1 + Q2;
}

__global__ void __launch_bounds__(64, 1)
hbv_kernel(const float* __restrict__ x,      // (T, N, 3)
           const float* __restrict__ praw,   // (T, N, 16, 4)
           const float* __restrict__ conv,   // (N, 2)
           float* __restrict__ out,          // (T, N)
           int T, int N)
{
    __shared__ __align__(16) char smem[LDS_BYTES];

    const int lane = threadIdx.x;
    const int n0 = blockIdx.x * 16;          // 16 n-chains per block
    const int nl = lane >> 2;                // n within block (0..15)
    const int m  = lane & 3;                 // ensemble member (0..3)
    const int n  = n0 + nl;
    // LDS word offset of this lane's param column within a slot.
    const int pofs = (nl >> 2) * (CHUNK_STRIDE / 4) + (nl & 3) * 64 + m;
    const int xofs = (SLOT_PARAM / 4) + 3 * nl;

    // --- Unit hydrograph (15 taps), identical across the 4 lanes of a quad ---
    const float a  = conv[2 * n + 0] * 2.9f;
    const float b  = conv[2 * n + 1] * 6.5f;
    const float aa = fmaxf(a, 0.0f) + 0.1f;
    const float th = fmaxf(b, 0.0f) + 0.5f;
    const float c0 = expf(-lgammaf(aa)) / powf(th, aa);
    float UH[LENF];
    float wsum = 0.0f;
#pragma unroll
    for (int k = 0; k < LENF; ++k) {
        const float tt = (float)k + 0.5f;
        const float w = c0 * powf(tt, aa - 1.0f) * expf(-tt / th);
        UH[k] = w;
        wsum += w;
    }
    const float rs = 1.0f / wsum;
#pragma unroll
    for (int k = 0; k < LENF; ++k) UH[k] *= rs;

    float acc[LENF - 1];                     // routing accumulators
#pragma unroll
    for (int k = 0; k < LENF - 1; ++k) acc[k] = 0.0f;

    float SNOWPACK = 0.001f, MELTWATER = 0.001f, SM = 0.001f,
          SUZ = 0.001f, SLZ = 0.001f;

    // Prologue: two batches in flight.
    stage_batch(praw, x, smem, 0, 0,  T, N, n0, lane);
    stage_batch(praw, x, smem, 1, KB, T, N, n0, lane);

    // Ping-pong register slabs for the one-step-ahead LDS->reg prefetch.
    float pA[14], fA[3], pB[14], fB[3];

#define LOAD_SLOT(P, F, SIDX)                                                 \
    {                                                                         \
        const float* slotf = (const float*)(bufp + (SIDX) * SLOT_BYTES);      \
        const float* pp = slotf + pofs;                                       \
        _Pragma("unroll")                                                     \
        for (int i = 0; i < 14; ++i) P[i] = pp[4 * i];                        \
        const float* xs = slotf + xofs;                                       \
        F[0] = xs[0]; F[1] = xs[1]; F[2] = xs[2];                             \
    }

#define STEP(P, F, TIDX)                                                      \
    {                                                                         \
        float v = dostep(P, F[0], F[1], F[2],                                 \
                         SNOWPACK, MELTWATER, SM, SUZ, SLZ);                  \
        v += qswap1(v);                                                       \
        v += qswap2(v);                                                       \
        const float q = v * 0.25f;                                            \
        const float e = fmaf(UH[0], q, acc[0]);                               \
        _Pragma("unroll")                                                     \
        for (int k = 0; k < LENF - 2; ++k)                                    \
            acc[k] = fmaf(UH[k + 1], q, acc[k + 1]);                          \
        acc[LENF - 2] = UH[LENF - 1] * q;                                     \
        if (m == 0) out[(size_t)(TIDX) * N + n] = e;                          \
    }

    const int nb_full = T / KB;              // unguarded full batches
    int t = 0;
    for (int bb = 0; bb < nb_full; ++bb) {
        // Batch bb's 35 loads are the oldest outstanding vmem ops; at most 35
        // newer ops (next batch's loads) need not be waited on. Prior batch's
        // <=7 stores are older and long-retired.
        __builtin_amdgcn_s_waitcnt(WAIT_VMCNT_35);
        __builtin_amdgcn_sched_barrier(0);

        const char* bufp = smem + (bb & 1) * BUF_BYTES;
        // Prefetch pipeline: LOAD(slot s+1) issued before STEP(slot s), so
        // each step's ds_read latency is hidden under the previous step's
        // dependency chain. No per-step branches in this body.
        LOAD_SLOT(pA, fA, 0);
        LOAD_SLOT(pB, fB, 1);
        STEP(pA, fA, t + 0);
        LOAD_SLOT(pA, fA, 2);
        STEP(pB, fB, t + 1);
        LOAD_SLOT(pB, fB, 3);
        STEP(pA, fA, t + 2);
        LOAD_SLOT(pA, fA, 4);
        STEP(pB, fB, t + 3);
        LOAD_SLOT(pB, fB, 5);
        STEP(pA, fA, t + 4);
        LOAD_SLOT(pA, fA, 6);
        STEP(pB, fB, t + 5);
        STEP(pA, fA, t + 6);
        t += KB;

        // ds_reads for this buffer are all complete (consumed by data dep);
        // lgkm(0) is free insurance before the async loads overwrite it.
        __builtin_amdgcn_s_waitcnt(WAIT_LGKM_0);
        __builtin_amdgcn_sched_barrier(0);
        stage_batch(praw, x, smem, bb & 1, (bb + 2) * KB, T, N, n0, lane);
    }

    // Tail: < KB guarded steps (T=365 -> exactly 1).
    if (t < T) {
        __builtin_amdgcn_s_waitcnt(WAIT_VMCNT_35);
        __builtin_amdgcn_sched_barrier(0);
        const char* bufp = smem + (nb_full & 1) * BUF_BYTES;
        for (int s = 0; s < KB && t < T; ++s, ++t) {
            LOAD_SLOT(pA, fA, s);
            STEP(pA, fA, t);
        }
    }
#undef LOAD_SLOT
#undef STEP
}

extern "C" void kernel_launch(void* const* d_in, const int* in_sizes, int n_in,
                              void* d_out, int out_size, void* d_ws, size_t ws_size,
                              hipStream_t stream)
{
    const float* x    = (const float*)d_in[0];  // (T, N, 3)
    const float* praw = (const float*)d_in[1];  // (T, N, 16, 4)
    const float* conv = (const float*)d_in[2];  // (N, 2)
    float* out = (float*)d_out;                 // (T, N)

    const int N = in_sizes[2] / 2;
    const int T = in_sizes[0] / (3 * N);

    const int grid = (N + 15) / 16;             // 16 chains/block, 1 wave/block
    hipLaunchKernelGGL(hbv_kernel, dim3(grid), dim3(64), 0, stream,
                       x, praw, conv, out, T, N);
}